// Round 2
// baseline (615.275 us; speedup 1.0000x reference)
//
#include <hip/hip_runtime.h>

// KacLayer: out[512][4096] = x @ W^T + b  +  Kac2( vec * Kac1( x ) )
//
//  ksched: per 1024-step window, dependency-round election (atomicMin, program
//          order preserved on shared columns), counting-sort by round, pad each
//          round segment to x64 with identity rotations on a window-unused
//          column, emit packed exec-order records -> d_ws. Bit-exact reorder.
//  kgemm : bf16-MFMA GEMM, out = x@W^T + b.
//  kwalk : 1 wave / 2 rows (independent __shared__ arrays), flat record
//          stream; same-round chunk pairing gives 4 independent rotations
//          in flight per iteration. No ballots, no barriers in hot loop.

#define DIM    4096
#define ROWS   512
#define NSTEPS 49152
#define WSTEPS 1024
#define NW2    (NSTEPS / WSTEPS)      // 48 windows per walk
#define NSLOT  (2 * NW2)              // 96 window slots
#define SLOT   2304                   // record capacity per slot (1024 + pad headroom)
#define MAXR   64

typedef short  short8 __attribute__((ext_vector_type(8)));
typedef __bf16 bf16x8 __attribute__((ext_vector_type(8)));
typedef float  f32x4  __attribute__((ext_vector_type(4)));

__device__ inline short f2bf(float f) {
    unsigned u = __builtin_bit_cast(unsigned, f);
    u += 0x7FFFu + ((u >> 16) & 1u);
    return (short)(u >> 16);
}
__device__ inline short8 pack8(float4 a, float4 b) {
    short8 r;
    r[0] = f2bf(a.x); r[1] = f2bf(a.y); r[2] = f2bf(a.z); r[3] = f2bf(a.w);
    r[4] = f2bf(b.x); r[5] = f2bf(b.y); r[6] = f2bf(b.z); r[7] = f2bf(b.w);
    return r;
}

// ---------------------------------------------------------------------------
// 1) schedule kernel: one block per 1024-step window
// ---------------------------------------------------------------------------
__global__ __launch_bounds__(1024) void ksched(
    const int* __restrict__ i1, const int* __restrict__ j1,
    const float* __restrict__ c1, const float* __restrict__ s1,
    const int* __restrict__ i2, const int* __restrict__ j2,
    const float* __restrict__ c2, const float* __restrict__ s2,
    uint4* __restrict__ recs, int* __restrict__ cnts) {

    __shared__ unsigned tbl[DIM];
    __shared__ int cnt[MAXR], off[MAXR], idx[MAXR];
    __shared__ int remaining, ucol;

    const int b    = blockIdx.x;            // 0..95
    const int walk = b / NW2;
    const int w    = b % NW2;
    const int t    = threadIdx.x;           // step within window
    const int gs   = w * WSTEPS + t;

    const int*   I = walk ? i2 : i1;
    const int*   J = walk ? j2 : j1;
    const float* C = walk ? c2 : c1;
    const float* S = walk ? s2 : s1;

    const int   li = I[gs], lj = J[gs];
    const float lc = C[gs], ls = S[gs];

    for (int k = t; k < DIM; k += WSTEPS) tbl[k] = 0xFFFFFFFFu;
    if (t < MAXR) { cnt[t] = 0; idx[t] = 0; }
    if (t == 0)   { remaining = WSTEPS; ucol = DIM; }
    __syncthreads();

    // ---- round election: winner = min pending step on BOTH its columns ----
    int myr = -1;
    int rr  = 0;
    for (;;) {
        if (myr < 0) {
            atomicMin(&tbl[li], (unsigned)t);
            atomicMin(&tbl[lj], (unsigned)t);
        }
        __syncthreads();
        const bool win = (myr < 0) && tbl[li] == (unsigned)t && tbl[lj] == (unsigned)t;
        __syncthreads();                                   // reads before resets
        if (win) {
            myr = rr;
            tbl[li] = 0xFFFFFFFFu; tbl[lj] = 0xFFFFFFFFu;  // winners' cols disjoint
            atomicSub(&remaining, 1);
        }
        ++rr;
        __syncthreads();
        if (remaining == 0 || rr >= MAXR) break;
    }
    if (myr < 0) myr = MAXR - 1;   // statistically unreachable

    // ---- per-round counts ----
    atomicAdd(&cnt[myr], 1);

    // ---- find a column unused in this window (for identity padding) ----
    for (int k = t; k < DIM; k += WSTEPS) tbl[k] = 0u;
    __syncthreads();
    tbl[li] = 1u; tbl[lj] = 1u;
    __syncthreads();
    for (int k = t; k < DIM; k += WSTEPS)
        if (tbl[k] == 0u) atomicMin(&ucol, k);             // >=2048 cols free
    __syncthreads();

    // ---- offsets (rounds padded to x64) ----
    if (t == 0) {
        int o = 0;
        for (int r = 0; r < MAXR; ++r) {
            off[r] = o;
            o += (cnt[r] + 63) & ~63;
        }
        cnts[b] = (o > SLOT) ? SLOT : o;
    }
    __syncthreads();

    uint4* slotp = recs + (size_t)b * SLOT;
    const int total = cnts[b];
    const unsigned uc = (unsigned)ucol;
    const uint4 padrec = { uc | (uc << 16), __builtin_bit_cast(unsigned, 1.0f),
                           __builtin_bit_cast(unsigned, 0.0f), 0xFFFFu };
    for (int k = t; k < total; k += WSTEPS) slotp[k] = padrec;
    __syncthreads();

    // ---- scatter (order within round irrelevant: rounds are column-disjoint)
    const int p = off[myr] + atomicAdd(&idx[myr], 1);
    if (p < SLOT) {
        uint4 r;
        r.x = (unsigned)li | ((unsigned)lj << 16);
        r.y = __builtin_bit_cast(unsigned, lc);
        r.z = __builtin_bit_cast(unsigned, ls);
        r.w = (unsigned)myr;
        slotp[p] = r;
    }
}

// ---------------------------------------------------------------------------
// 2) bf16 MFMA GEMM: out = x @ W^T + b      (BM=64, BN=128, BK=64, 256 thr)
// ---------------------------------------------------------------------------
#define BM  64
#define BN  128
#define BK  64
#define LDT 72

__global__ __launch_bounds__(256) void kgemm(const float* __restrict__ X, const float* __restrict__ W,
                                             const float* __restrict__ bias, float* __restrict__ out) {
    __shared__ short As[BM * LDT];
    __shared__ short Bs[BN * LDT];
    const int tid  = threadIdx.x;
    const int bn   = (blockIdx.x & 31) * BN;
    const int bm   = (blockIdx.x >> 5) * BM;
    const int lane = tid & 63;
    const int wv   = tid >> 6;
    const int wr   = (wv >> 1) * 32;
    const int wc   = (wv & 1) * 64;
    const int fr   = lane & 15;
    const int ke   = (lane >> 4) * 8;

    f32x4 acc[2][4];
#pragma unroll
    for (int m = 0; m < 2; ++m)
#pragma unroll
        for (int n = 0; n < 4; ++n) acc[m][n] = (f32x4){0.f, 0.f, 0.f, 0.f};

    const int tr = tid >> 2;
    const int tc = (tid & 3) << 4;

    for (int kt = 0; kt < DIM / BK; ++kt) {
        const int k0 = kt * BK;
        float4 ra[4], rb[2][4];
        {
            const float4* ga = (const float4*)(X + (size_t)(bm + tr) * DIM + k0 + tc);
#pragma unroll
            for (int q = 0; q < 4; ++q) ra[q] = ga[q];
#pragma unroll
            for (int h = 0; h < 2; ++h) {
                const float4* gb = (const float4*)(W + (size_t)(bn + h * 64 + tr) * DIM + k0 + tc);
#pragma unroll
                for (int q = 0; q < 4; ++q) rb[h][q] = gb[q];
            }
        }
        __syncthreads();
        *(short8*)&As[tr * LDT + tc]     = pack8(ra[0], ra[1]);
        *(short8*)&As[tr * LDT + tc + 8] = pack8(ra[2], ra[3]);
#pragma unroll
        for (int h = 0; h < 2; ++h) {
            *(short8*)&Bs[(h * 64 + tr) * LDT + tc]     = pack8(rb[h][0], rb[h][1]);
            *(short8*)&Bs[(h * 64 + tr) * LDT + tc + 8] = pack8(rb[h][2], rb[h][3]);
        }
        __syncthreads();
#pragma unroll
        for (int kk = 0; kk < BK; kk += 32) {
            short8 af[2], bf[4];
#pragma unroll
            for (int m = 0; m < 2; ++m)
                af[m] = *(const short8*)&As[(wr + m * 16 + fr) * LDT + kk + ke];
#pragma unroll
            for (int n = 0; n < 4; ++n)
                bf[n] = *(const short8*)&Bs[(wc + n * 16 + fr) * LDT + kk + ke];
#pragma unroll
            for (int m = 0; m < 2; ++m)
#pragma unroll
                for (int n = 0; n < 4; ++n)
                    acc[m][n] = __builtin_amdgcn_mfma_f32_16x16x32_bf16(
                        __builtin_bit_cast(bf16x8, af[m]),
                        __builtin_bit_cast(bf16x8, bf[n]),
                        acc[m][n], 0, 0, 0);
        }
    }
#pragma unroll
    for (int n = 0; n < 4; ++n) {
        const int col = bn + wc + n * 16 + fr;
        const float bv = bias[col];
#pragma unroll
        for (int m = 0; m < 2; ++m) {
            const int rbase = bm + wr + m * 16 + (lane >> 4) * 4;
#pragma unroll
            for (int r = 0; r < 4; ++r)
                out[(size_t)(rbase + r) * DIM + col] = acc[m][n][r] + bv;
        }
    }
}

// ---------------------------------------------------------------------------
// 3) walk kernel: 1 wave per 2 rows, flat record stream, chunk pairing
// ---------------------------------------------------------------------------
__global__ __launch_bounds__(64) void kwalk(const float* __restrict__ X, const float* __restrict__ vec,
                                            const uint4* __restrict__ recs, const int* __restrict__ cnts,
                                            float* __restrict__ out) {
    __shared__ float rowA[DIM];
    __shared__ float rowB[DIM];
    const int pr   = blockIdx.x;          // row pair
    const int lane = threadIdx.x;
    const int rA   = pr * 2, rB = pr * 2 + 1;

    float4* a4 = (float4*)rowA;
    float4* b4 = (float4*)rowB;
    {
        const float4* xa = (const float4*)(X + (size_t)rA * DIM);
        const float4* xb = (const float4*)(X + (size_t)rB * DIM);
        for (int c = lane; c < DIM / 4; c += 64) { a4[c] = xa[c]; b4[c] = xb[c]; }
    }
    __syncthreads();

    for (int walk = 0; walk < 2; ++walk) {
        if (walk == 1) {
            __syncthreads();
            const float4* v4 = (const float4*)vec;
            for (int c = lane; c < DIM / 4; c += 64) {
                const float4 v = v4[c];
                float4 ta = a4[c], tb = b4[c];
                ta.x *= v.x; ta.y *= v.y; ta.z *= v.z; ta.w *= v.w;
                tb.x *= v.x; tb.y *= v.y; tb.z *= v.z; tb.w *= v.w;
                a4[c] = ta; b4[c] = tb;
            }
            __syncthreads();
        }
        for (int w = 0; w < NW2; ++w) {
            const int slot = walk * NW2 + w;
            const int n = cnts[slot];
            const uint4* base = recs + (size_t)slot * SLOT;
            int c = 0;
            while (c < n) {
                const uint4 q0 = base[c + lane];
                bool pair = (c + 64 < n);
                uint4 q1;
                if (pair) {
                    q1   = base[c + 64 + lane];
                    pair = (__builtin_amdgcn_readfirstlane((int)q1.w) ==
                            __builtin_amdgcn_readfirstlane((int)q0.w));
                }
                const int   i0 = q0.x & 0xFFFF, j0 = q0.x >> 16;
                const float c0 = __builtin_bit_cast(float, q0.y);
                const float s0 = __builtin_bit_cast(float, q0.z);
                if (pair) {
                    const int   i1 = q1.x & 0xFFFF, j1 = q1.x >> 16;
                    const float c1 = __builtin_bit_cast(float, q1.y);
                    const float s1 = __builtin_bit_cast(float, q1.z);
                    // same round => all 4 rotations column-disjoint: issue all
                    // 8 gathers before any scatter (source order enforces it).
                    const float ai0 = rowA[i0], aj0 = rowA[j0];
                    const float ai1 = rowA[i1], aj1 = rowA[j1];
                    const float bi0 = rowB[i0], bj0 = rowB[j0];
                    const float bi1 = rowB[i1], bj1 = rowB[j1];
                    rowA[i0] = fmaf(c0, ai0,  s0 * aj0);
                    rowA[j0] = fmaf(c0, aj0, -s0 * ai0);
                    rowA[i1] = fmaf(c1, ai1,  s1 * aj1);
                    rowA[j1] = fmaf(c1, aj1, -s1 * ai1);
                    rowB[i0] = fmaf(c0, bi0,  s0 * bj0);
                    rowB[j0] = fmaf(c0, bj0, -s0 * bi0);
                    rowB[i1] = fmaf(c1, bi1,  s1 * bj1);
                    rowB[j1] = fmaf(c1, bj1, -s1 * bi1);
                    c += 128;
                } else {
                    const float ai0 = rowA[i0], aj0 = rowA[j0];
                    const float bi0 = rowB[i0], bj0 = rowB[j0];
                    rowA[i0] = fmaf(c0, ai0,  s0 * aj0);
                    rowA[j0] = fmaf(c0, aj0, -s0 * ai0);
                    rowB[i0] = fmaf(c0, bi0,  s0 * bj0);
                    rowB[j0] = fmaf(c0, bj0, -s0 * bi0);
                    c += 64;
                }
            }
        }
    }
    __syncthreads();

    float4* oa = (float4*)(out + (size_t)rA * DIM);
    float4* ob = (float4*)(out + (size_t)rB * DIM);
    for (int c = lane; c < DIM / 4; c += 64) {
        float4 ta = oa[c], tb = ob[c];
        const float4 sa = a4[c], sb = b4[c];
        ta.x += sa.x; ta.y += sa.y; ta.z += sa.z; ta.w += sa.w;
        tb.x += sb.x; tb.y += sb.y; tb.z += sb.z; tb.w += sb.w;
        oa[c] = ta; ob[c] = tb;
    }
}

// ---------------------------------------------------------------------------
extern "C" void kernel_launch(void* const* d_in, const int* in_sizes, int n_in,
                              void* d_out, int out_size, void* d_ws, size_t ws_size,
                              hipStream_t stream) {
    const float* X    = (const float*)d_in[0];
    const float* W    = (const float*)d_in[1];
    const float* bias = (const float*)d_in[2];
    const float* vec  = (const float*)d_in[3];
    const int*   i1   = (const int*)d_in[4];
    const int*   j1   = (const int*)d_in[5];
    const float* c1   = (const float*)d_in[6];
    const float* s1   = (const float*)d_in[7];
    const int*   i2   = (const int*)d_in[8];
    const int*   j2   = (const int*)d_in[9];
    const float* c2   = (const float*)d_in[10];
    const float* s2   = (const float*)d_in[11];
    float* out = (float*)d_out;

    uint4* recs = (uint4*)d_ws;                        // 96*2304*16B = 3.46 MiB
    int*   cnts = (int*)((char*)d_ws + (size_t)NSLOT * SLOT * 16);

    hipLaunchKernelGGL(ksched, dim3(NSLOT), dim3(WSTEPS), 0, stream,
                       i1, j1, c1, s1, i2, j2, c2, s2, recs, cnts);
    hipLaunchKernelGGL(kgemm,  dim3(256), dim3(256), 0, stream, X, W, bias, out);
    hipLaunchKernelGGL(kwalk,  dim3(ROWS / 2), dim3(64), 0, stream, X, vec, recs, cnts, out);
}

// Round 3
// 348.168 us; speedup vs baseline: 1.7672x; 1.7672x over previous
//
#include <hip/hip_runtime.h>

// KacLayer: out[512][4096] = x @ W^T + b  +  Kac2( vec * Kac1( x ) )
//
//  ksched: per 1024-step window, dependency-round election (ping-pong
//          atomicMin, 2 barriers/round, program order preserved on shared
//          columns), rounds padded to x128 with identity records on a
//          window-unused column, packed exec-order records -> d_ws.
//          Reordering commuting Givens rotations is bit-exact.
//  kgemm : bf16-MFMA GEMM, out = x@W^T + b.
//  kwalk : one wave / 2 rows in LDS; flat iteration space, 128 records per
//          iteration (guaranteed column-disjoint), records prefetched 2
//          iterations ahead with fully static addressing. No ballots, no
//          barriers, no data-dependent addresses in the hot loop.

#define DIM    4096
#define ROWS   512
#define NSTEPS 49152
#define WSTEPS 1024
#define NW2    (NSTEPS / WSTEPS)      // 48 windows per walk
#define NSLOT  (2 * NW2)              // 96 window slots
#define SLOT   3072                   // record capacity per slot
#define MAXR   64
#define CHUNK  128                    // records per kwalk iteration

typedef short  short8 __attribute__((ext_vector_type(8)));
typedef __bf16 bf16x8 __attribute__((ext_vector_type(8)));
typedef float  f32x4  __attribute__((ext_vector_type(4)));

__device__ inline short f2bf(float f) {
    unsigned u = __builtin_bit_cast(unsigned, f);
    u += 0x7FFFu + ((u >> 16) & 1u);
    return (short)(u >> 16);
}
__device__ inline short8 pack8(float4 a, float4 b) {
    short8 r;
    r[0] = f2bf(a.x); r[1] = f2bf(a.y); r[2] = f2bf(a.z); r[3] = f2bf(a.w);
    r[4] = f2bf(b.x); r[5] = f2bf(b.y); r[6] = f2bf(b.z); r[7] = f2bf(b.w);
    return r;
}
__device__ inline float bitf(unsigned u) { return __builtin_bit_cast(float, u); }

// ---------------------------------------------------------------------------
// 1) schedule kernel: one block per 1024-step window
// ---------------------------------------------------------------------------
__global__ __launch_bounds__(1024) void ksched(
    const int* __restrict__ i1, const int* __restrict__ j1,
    const float* __restrict__ c1, const float* __restrict__ s1,
    const int* __restrict__ i2, const int* __restrict__ j2,
    const float* __restrict__ c2, const float* __restrict__ s2,
    uint4* __restrict__ recs, int* __restrict__ cnts) {

    __shared__ unsigned tblA[DIM], tblB[DIM];
    __shared__ int cnt[MAXR], off[MAXR], idx[MAXR];
    __shared__ int ucol, stotal;

    const int b    = blockIdx.x;            // 0..95
    const int walk = b / NW2;
    const int w    = b % NW2;
    const int t    = threadIdx.x;
    const int gs   = w * WSTEPS + t;

    const int*   I = walk ? i2 : i1;
    const int*   J = walk ? j2 : j1;
    const float* C = walk ? c2 : c1;
    const float* S = walk ? s2 : s1;

    const int   li = I[gs], lj = J[gs];
    const float lc = C[gs], ls = S[gs];

    if (t < MAXR) { cnt[t] = 0; idx[t] = 0; }
    if (t == 0)   ucol = DIM;
    tblA[li] = 0xFFFFFFFFu; tblA[lj] = 0xFFFFFFFFu;   // clear own cols, round 0
    __syncthreads();

    // ---- election: winner = min pending step on BOTH its columns ----------
    // 2 barriers/round: ping-pong buffers; losers pre-clear next buffer.
    unsigned* cur = tblA;
    unsigned* nxt = tblB;
    int  myr     = -1;
    bool pending = true;
    for (int rr = 0; rr < MAXR; ++rr) {
        if (pending) { atomicMin(&cur[li], (unsigned)t); atomicMin(&cur[lj], (unsigned)t); }
        __syncthreads();
        if (pending && cur[li] == (unsigned)t && cur[lj] == (unsigned)t) { myr = rr; pending = false; }
        if (pending) { nxt[li] = 0xFFFFFFFFu; nxt[lj] = 0xFFFFFFFFu; }
        const int np = __syncthreads_count(pending ? 1 : 0);
        if (np == 0) break;
        unsigned* tmp = cur; cur = nxt; nxt = tmp;
    }
    if (myr < 0) myr = MAXR - 1;            // statistically unreachable
    atomicAdd(&cnt[myr], 1);

    // ---- a column unused in this window (identity padding target) ---------
    for (int k = t; k < DIM; k += WSTEPS) tblA[k] = 0u;
    __syncthreads();
    tblA[li] = 1u; tblA[lj] = 1u;
    __syncthreads();
    for (int k = t; k < DIM; k += WSTEPS)
        if (tblA[k] == 0u) atomicMin(&ucol, k);       // >=2048 cols unused
    __syncthreads();                                  // cnt[] and ucol final

    // ---- offsets: rounds padded to x128 ------------------------------------
    if (t == 0) {
        int o = 0;
        for (int r = 0; r < MAXR; ++r) {
            off[r] = o;
            o += (cnt[r] + CHUNK - 1) & ~(CHUNK - 1);
        }
        stotal  = (o > SLOT) ? SLOT : o;
        cnts[b] = stotal;
    }
    __syncthreads();

    uint4* slotp = recs + (size_t)b * SLOT;
    const unsigned uc = (unsigned)ucol;
    const uint4 padrec = { uc | (uc << 16), __builtin_bit_cast(unsigned, 1.0f),
                           __builtin_bit_cast(unsigned, 0.0f), 0u };
    for (int k = t; k < stotal; k += WSTEPS) slotp[k] = padrec;
    __syncthreads();

    // ---- scatter (order within a round irrelevant: columns disjoint) ------
    const int p = off[myr] + atomicAdd(&idx[myr], 1);
    if (p < SLOT) {
        uint4 r;
        r.x = (unsigned)li | ((unsigned)lj << 16);
        r.y = __builtin_bit_cast(unsigned, lc);
        r.z = __builtin_bit_cast(unsigned, ls);
        r.w = (unsigned)myr;
        slotp[p] = r;
    }
}

// ---------------------------------------------------------------------------
// 2) bf16 MFMA GEMM: out = x @ W^T + b      (BM=64, BN=128, BK=64, 256 thr)
// ---------------------------------------------------------------------------
#define BM  64
#define BN  128
#define BK  64
#define LDT 72

__global__ __launch_bounds__(256) void kgemm(const float* __restrict__ X, const float* __restrict__ W,
                                             const float* __restrict__ bias, float* __restrict__ out) {
    __shared__ short As[BM * LDT];
    __shared__ short Bs[BN * LDT];
    const int tid  = threadIdx.x;
    const int bn   = (blockIdx.x & 31) * BN;
    const int bm   = (blockIdx.x >> 5) * BM;
    const int lane = tid & 63;
    const int wv   = tid >> 6;
    const int wr   = (wv >> 1) * 32;
    const int wc   = (wv & 1) * 64;
    const int fr   = lane & 15;
    const int ke   = (lane >> 4) * 8;

    f32x4 acc[2][4];
#pragma unroll
    for (int m = 0; m < 2; ++m)
#pragma unroll
        for (int n = 0; n < 4; ++n) acc[m][n] = (f32x4){0.f, 0.f, 0.f, 0.f};

    const int tr = tid >> 2;
    const int tc = (tid & 3) << 4;

    for (int kt = 0; kt < DIM / BK; ++kt) {
        const int k0 = kt * BK;
        float4 ra[4], rb[2][4];
        {
            const float4* ga = (const float4*)(X + (size_t)(bm + tr) * DIM + k0 + tc);
#pragma unroll
            for (int q = 0; q < 4; ++q) ra[q] = ga[q];
#pragma unroll
            for (int h = 0; h < 2; ++h) {
                const float4* gb = (const float4*)(W + (size_t)(bn + h * 64 + tr) * DIM + k0 + tc);
#pragma unroll
                for (int q = 0; q < 4; ++q) rb[h][q] = gb[q];
            }
        }
        __syncthreads();
        *(short8*)&As[tr * LDT + tc]     = pack8(ra[0], ra[1]);
        *(short8*)&As[tr * LDT + tc + 8] = pack8(ra[2], ra[3]);
#pragma unroll
        for (int h = 0; h < 2; ++h) {
            *(short8*)&Bs[(h * 64 + tr) * LDT + tc]     = pack8(rb[h][0], rb[h][1]);
            *(short8*)&Bs[(h * 64 + tr) * LDT + tc + 8] = pack8(rb[h][2], rb[h][3]);
        }
        __syncthreads();
#pragma unroll
        for (int kk = 0; kk < BK; kk += 32) {
            short8 af[2], bf[4];
#pragma unroll
            for (int m = 0; m < 2; ++m)
                af[m] = *(const short8*)&As[(wr + m * 16 + fr) * LDT + kk + ke];
#pragma unroll
            for (int n = 0; n < 4; ++n)
                bf[n] = *(const short8*)&Bs[(wc + n * 16 + fr) * LDT + kk + ke];
#pragma unroll
            for (int m = 0; m < 2; ++m)
#pragma unroll
                for (int n = 0; n < 4; ++n)
                    acc[m][n] = __builtin_amdgcn_mfma_f32_16x16x32_bf16(
                        __builtin_bit_cast(bf16x8, af[m]),
                        __builtin_bit_cast(bf16x8, bf[n]),
                        acc[m][n], 0, 0, 0);
        }
    }
#pragma unroll
    for (int n = 0; n < 4; ++n) {
        const int col = bn + wc + n * 16 + fr;
        const float bv = bias[col];
#pragma unroll
        for (int m = 0; m < 2; ++m) {
            const int rbase = bm + wr + m * 16 + (lane >> 4) * 4;
#pragma unroll
            for (int r = 0; r < 4; ++r)
                out[(size_t)(rbase + r) * DIM + col] = acc[m][n][r] + bv;
        }
    }
}

// ---------------------------------------------------------------------------
// 3) walk kernel: 1 wave / 2 rows, static addressing, 2-iteration prefetch
// ---------------------------------------------------------------------------
__global__ __launch_bounds__(64) void kwalk(const float* __restrict__ X, const float* __restrict__ vec,
                                            const uint4* __restrict__ recs, const int* __restrict__ cnts,
                                            float* __restrict__ out) {
    __shared__ float rowA[DIM];
    __shared__ float rowB[DIM];
    const int pr   = blockIdx.x;
    const int lane = threadIdx.x;
    const int rA   = pr * 2, rB = pr * 2 + 1;

    float4* a4 = (float4*)rowA;
    float4* b4 = (float4*)rowB;
    {
        const float4* xa = (const float4*)(X + (size_t)rA * DIM);
        const float4* xb = (const float4*)(X + (size_t)rB * DIM);
        for (int c = lane; c < DIM / 4; c += 64) { a4[c] = xa[c]; b4[c] = xb[c]; }
    }
    // single wave: in-order DS pipe makes LDS wave-synchronous, no barriers.

    // per-slot iteration counts, kept in registers, fetched via shuffle
    const int cA = cnts[lane] / CHUNK;                                  // slots 0..63
    const int cB = cnts[(lane < NSLOT - 64) ? (64 + lane) : 64] / CHUNK; // slots 64..95

    // prologue: records for iterations 0 and 1 of slot 0
    uint4 q0 = recs[lane],       q1 = recs[64 + lane];
    uint4 n0 = recs[128 + lane], n1 = recs[192 + lane];

    for (int slot = 0; slot < NSLOT; ++slot) {
        if (slot == NW2) {
            // between walks: yp = vec * yp
            const float4* v4 = (const float4*)vec;
            for (int c = lane; c < DIM / 4; c += 64) {
                const float4 v = v4[c];
                float4 ta = a4[c], tb = b4[c];
                ta.x *= v.x; ta.y *= v.y; ta.z *= v.z; ta.w *= v.w;
                tb.x *= v.x; tb.y *= v.y; tb.z *= v.z; tb.w *= v.w;
                a4[c] = ta; b4[c] = tb;
            }
        }
        const int nit = (slot < 64) ? __shfl(cA, slot) : __shfl(cB, slot - 64);
        const uint4* wb = recs + (size_t)slot * SLOT;
        const uint4* nb = recs + (size_t)((slot + 1 < NSLOT) ? slot + 1 : slot) * SLOT;

        for (int it = 0; it < nit; ++it) {
            // prefetch records for iteration it+2 (addresses static; every
            // slot has >=8 iterations so at most one boundary crossing)
            const int idx2 = it + 2;
            const uint4* p2 = (idx2 < nit) ? (wb + (size_t)idx2 * CHUNK)
                                           : (nb + (size_t)(idx2 - nit) * CHUNK);
            const uint4 m0 = p2[lane];
            const uint4 m1 = p2[64 + lane];

            // process current 128 records (column-disjoint by construction):
            // all 8 gathers before any scatter.
            const int   i0 = q0.x & 0xFFFF, j0 = q0.x >> 16;
            const int   i1 = q1.x & 0xFFFF, j1 = q1.x >> 16;
            const float c0 = bitf(q0.y), s0 = bitf(q0.z);
            const float c1 = bitf(q1.y), s1 = bitf(q1.z);

            const float ai0 = rowA[i0], aj0 = rowA[j0];
            const float ai1 = rowA[i1], aj1 = rowA[j1];
            const float bi0 = rowB[i0], bj0 = rowB[j0];
            const float bi1 = rowB[i1], bj1 = rowB[j1];
            rowA[i0] = fmaf(c0, ai0,  s0 * aj0);
            rowA[j0] = fmaf(c0, aj0, -s0 * ai0);
            rowA[i1] = fmaf(c1, ai1,  s1 * aj1);
            rowA[j1] = fmaf(c1, aj1, -s1 * ai1);
            rowB[i0] = fmaf(c0, bi0,  s0 * bj0);
            rowB[j0] = fmaf(c0, bj0, -s0 * bi0);
            rowB[i1] = fmaf(c1, bi1,  s1 * bj1);
            rowB[j1] = fmaf(c1, bj1, -s1 * bi1);

            q0 = n0; q1 = n1; n0 = m0; n1 = m1;
        }
    }

    float4* oa = (float4*)(out + (size_t)rA * DIM);
    float4* ob = (float4*)(out + (size_t)rB * DIM);
    for (int c = lane; c < DIM / 4; c += 64) {
        float4 ta = oa[c], tb = ob[c];
        const float4 sa = a4[c], sb = b4[c];
        ta.x += sa.x; ta.y += sa.y; ta.z += sa.z; ta.w += sa.w;
        tb.x += sb.x; tb.y += sb.y; tb.z += sb.z; tb.w += sb.w;
        oa[c] = ta; ob[c] = tb;
    }
}

// ---------------------------------------------------------------------------
extern "C" void kernel_launch(void* const* d_in, const int* in_sizes, int n_in,
                              void* d_out, int out_size, void* d_ws, size_t ws_size,
                              hipStream_t stream) {
    const float* X    = (const float*)d_in[0];
    const float* W    = (const float*)d_in[1];
    const float* bias = (const float*)d_in[2];
    const float* vec  = (const float*)d_in[3];
    const int*   i1   = (const int*)d_in[4];
    const int*   j1   = (const int*)d_in[5];
    const float* c1   = (const float*)d_in[6];
    const float* s1   = (const float*)d_in[7];
    const int*   i2   = (const int*)d_in[8];
    const int*   j2   = (const int*)d_in[9];
    const float* c2   = (const float*)d_in[10];
    const float* s2   = (const float*)d_in[11];
    float* out = (float*)d_out;

    uint4* recs = (uint4*)d_ws;                        // 96*3072*16B = 4.5 MiB
    int*   cnts = (int*)((char*)d_ws + (size_t)NSLOT * SLOT * 16);

    hipLaunchKernelGGL(ksched, dim3(NSLOT), dim3(WSTEPS), 0, stream,
                       i1, j1, c1, s1, i2, j2, c2, s2, recs, cnts);
    hipLaunchKernelGGL(kgemm,  dim3(256), dim3(256), 0, stream, X, W, bias, out);
    hipLaunchKernelGGL(kwalk,  dim3(ROWS / 2), dim3(64), 0, stream, X, vec, recs, cnts, out);
}